// Round 4
// baseline (686.121 us; speedup 1.0000x reference)
//
#include <hip/hip_runtime.h>

typedef __attribute__((ext_vector_type(8))) short bf16x8;
typedef __attribute__((ext_vector_type(4))) float f32x4;
typedef __attribute__((ext_vector_type(4))) short short4v;

__device__ __forceinline__ unsigned short f2bf(float x){
  unsigned u = __float_as_uint(x);
  return (unsigned short)((u + 0x7FFFu + ((u>>16)&1u)) >> 16);
}
__device__ __forceinline__ float bf2f(unsigned short b){
  return __uint_as_float(((unsigned)b)<<16);
}

typedef const __attribute__((address_space(1))) void* gas_t;
typedef __attribute__((address_space(3))) void* las_t;
__device__ __forceinline__ void gl16(const void* g, void* l){
  __builtin_amdgcn_global_load_lds((gas_t)g, (las_t)l, 16, 0, 0);
}

// ---------------- workspace layout (bytes), ws_size ~784 MiB ----------------
static constexpr size_t O_FHI  = 0;              // fhi bf16 [25088][2048] 102760448 (later xxt f32 134217728)
static constexpr size_t O_FLO  = 102760448;      // flo bf16 [25088][2048] 102760448
static constexpr size_t O_XHI  = 205520896;      // x_hi bf16 [128][512][256] 33554432
static constexpr size_t O_XLO  = 239075328;      // x_lo bf16 (later ypad [b][8][256][64]) 33554432
static constexpr size_t O_XT   = 272629760;      // xT bf16 [128][224][512] 29360128
static constexpr size_t O_AMAT = 301989888;      // a bf16 [128][512][512] 67108864
static constexpr size_t O_WH   = 369098752;      // wh bf16 [512][2048] 2097152
static constexpr size_t O_WL   = 371195904;      // wl
static constexpr size_t O_W3B  = 373293056;      // w3c bf16 [8][9][512][64] 4718592
static constexpr size_t O_PAR  = 378011648;      // s1,t1,s2,t2
static constexpr size_t O_FC1T = 378019840;      // fc1T f32 [512][200]
static constexpr size_t O_FC2T = 378429440;      // fc2T f32 [200][200]
static constexpr size_t O_ZBAR = 378589440;      // zbar f32 [128][512] (sum)

// ---------------- prep kernels ----------------
__global__ void k_params(const float* br, const float* g1, const float* be1, const float* m1, const float* v1,
                         const float* b3, const float* g2, const float* be2, const float* m2, const float* v2,
                         float* par){
  int c = blockIdx.x*256 + threadIdx.x;
  if (c >= 512) return;
  float s1 = g1[c] * rsqrtf(v1[c] + 1e-5f);
  par[c] = s1;
  par[512+c] = (br[c]-m1[c])*s1 + be1[c];
  float s2 = g2[c] * rsqrtf(v2[c] + 1e-5f);
  par[1024+c] = s2;
  par[1536+c] = (b3[c]-m2[c])*s2 + be2[c];
}

__global__ void k_wrhl(const float* wr, unsigned short* wh, unsigned short* wl){
  int k = blockIdx.x*256 + threadIdx.x;
  int c = blockIdx.y;
  float v = wr[(size_t)c*2048 + k];
  unsigned short h = f2bf(v);
  wh[(size_t)c*2048 + k] = h;
  wl[(size_t)c*2048 + k] = f2bf(v - bf2f(h));
}

// w3c[ci0b][tap][co][cio] = bf16(w3[co][ci0b*64+cio][tap])
__global__ void k_w3c(const float* w3, unsigned short* w3c){
  int k = blockIdx.x*256 + threadIdx.x;     // < 4608
  int co = blockIdx.y;
  int ci0b = k/576; int r2 = k - ci0b*576;
  int tap = r2>>6;  int cio = r2&63;
  w3c[(((size_t)ci0b*9 + tap)*512 + co)*64 + cio] =
      f2bf(w3[((size_t)co*512 + ci0b*64 + cio)*9 + tap]);
}

__global__ void k_fc1t(const float* w, float* wt){
  int i = blockIdx.x*256 + threadIdx.x;
  int k = i/200, j = i - k*200;
  wt[i] = w[j*512 + k];
}
__global__ void k_fc2t(const float* w, float* wt){
  int i = blockIdx.x*256 + threadIdx.x;
  if (i >= 200*200) return;
  int k = i/200, j = i - k*200;
  wt[i] = w[j*200 + k];
}

// zero cols [192,256) of xhi/xlo rows [128*512] (conv1 later overwrites 192..195)
__global__ __launch_bounds__(256) void k_zeropad(unsigned short* xhi, unsigned short* xlo){
  int rr = blockIdx.x*256 + threadIdx.x;     // 65536 rows
  float4 z = {0.f,0.f,0.f,0.f};
  float4* a = (float4*)(xhi + (size_t)rr*256 + 192);
  float4* b = (float4*)(xlo + (size_t)rr*256 + 192);
  #pragma unroll
  for (int j=0;j<8;++j){ a[j] = z; b[j] = z; }
}

// zero the 60 border rows of each ypad[b][cib][256][64] tile
__global__ __launch_bounds__(256) void k_zeroyb(unsigned short* ypad){
  int tile = blockIdx.x;                     // 1024 = b*8+cib
  int r = threadIdx.x;
  if (r >= 256) return;
  int hi = r>>4, lo = r&15;
  bool pad = (hi==0)||(hi==15)||(lo==0)||(lo==15);
  if (!pad) return;
  float4 z = {0.f,0.f,0.f,0.f};
  float4* p = (float4*)(ypad + ((size_t)tile*256 + r)*64);
  #pragma unroll
  for (int j=0;j<8;++j) p[j] = z;
}

// transpose+split feature -> dense fhi/flo bf16 [b*196+p][2048]
__global__ __launch_bounds__(256) void k_featT(const float* __restrict__ feat,
        unsigned short* __restrict__ fhi, unsigned short* __restrict__ flo){
  __shared__ float tile[64][33];
  int b = blockIdx.z;
  int ci0 = blockIdx.y*64, p0 = blockIdx.x*32;
  int t = threadIdx.x;
  int j = t & 31, i0 = t >> 5;
  for (int rep=0; rep<8; ++rep){
    int i = rep*8 + i0;
    int p = p0 + j;
    tile[i][j] = (p<196) ? feat[((size_t)b*2048 + ci0 + i)*196 + p] : 0.f;
  }
  __syncthreads();
  int ii = t & 63, jj0 = t >> 6;
  for (int rep=0; rep<8; ++rep){
    int jj = rep*4 + jj0;
    int p = p0 + jj;
    if (p < 196){
      float v = tile[ii][jj];
      unsigned short h = f2bf(v);
      size_t o = ((size_t)b*196 + p)*2048 + ci0 + ii;
      fhi[o] = h;
      flo[o] = f2bf(v - bf2f(h));
    }
  }
}

// ---------------- conv1 as one dense GEMM: [512co] x [25088 g] , K=3x2048 seg ----------------
__global__ __launch_bounds__(256) void k_conv1(
    const unsigned short* __restrict__ fhi, const unsigned short* __restrict__ flo,
    const unsigned short* __restrict__ wh,  const unsigned short* __restrict__ wl,
    const float* __restrict__ par,
    unsigned short* __restrict__ xhi, unsigned short* __restrict__ xlo,
    unsigned short* __restrict__ xT){
  __shared__ char lds[32768];
  char* Als = lds; char* Bls = lds + 16384;
  int lin = blockIdx.x;                       // 784 blocks
  int sz  = (lin&7)*98 + (lin>>3);            // XCD swizzle (784%8==0)
  int mt = sz&3;                              // co tile: 4 consecutive share B
  int gt = sz>>2;                             // 0..195
  int c0 = mt*128;
  size_t g0 = (size_t)gt*128;
  int t = threadIdx.x, lane = t&63, wid = t>>6, wm = wid&1, wn = wid>>1;
  int fq = lane>>4, fr = lane&15;
  f32x4 acc[4][4] = {};
  for (int it=0; it<96; ++it){
    int seg = it>>5, kk0 = (it&31)*64;
    const unsigned short* As = (seg<2) ? wh : wl;
    const unsigned short* Bs = (seg==1) ? flo : fhi;
    __syncthreads();
    #pragma unroll
    for (int r=0;r<4;++r){
      int L = r*256 + t;
      int row = L>>3, cs = ((L&7)^(row&7))*8;
      gl16(As + (size_t)(c0+row)*2048 + kk0 + cs, Als + L*16);
      gl16(Bs + (g0+row)*2048 + kk0 + cs, Bls + L*16);
    }
    __syncthreads();
    #pragma unroll
    for (int ks=0; ks<2; ++ks){
      int kb = ks*64 + fq*16;
      bf16x8 af[4];
      #pragma unroll
      for (int m=0;m<4;++m){
        int row = wm*64 + m*16 + fr;
        af[m] = *(const bf16x8*)(Als + row*128 + (kb ^ ((row&7)<<4)));
      }
      #pragma unroll
      for (int n=0;n<4;++n){
        int row = wn*64 + n*16 + fr;
        bf16x8 bff = *(const bf16x8*)(Bls + row*128 + (kb ^ ((row&7)<<4)));
        #pragma unroll
        for (int m=0;m<4;++m)
          acc[m][n] = __builtin_amdgcn_mfma_f32_16x16x32_bf16(af[m], bff, acc[m][n],0,0,0);
      }
    }
  }
  const float* s1 = par; const float* t1 = par+512;
  for (int m=0;m<4;++m){
    int cb = c0 + wm*64 + m*16 + fq*4;
    float sc[4], sh[4];
    for (int j=0;j<4;++j){ sc[j]=s1[cb+j]; sh[j]=t1[cb+j]; }
    for (int n=0;n<4;++n){
      int gg = (int)g0 + wn*64 + n*16 + fr;
      int b = gg/196, p = gg - b*196;
      unsigned short hs[4];
      for (int j=0;j<4;++j){
        float v = fmaxf(acc[m][n][j]*sc[j]+sh[j], 0.f);
        unsigned short h = f2bf(v);
        hs[j] = h;
        size_t ic = (size_t)b*512 + cb + j;
        xhi[ic*256 + p] = h;
        xlo[ic*256 + p] = f2bf(v - bf2f(h));
      }
      *(short4v*)(xT + ((size_t)b*224 + p)*512 + cb) = *(short4v*)hs;
    }
  }
}

// ---------------- xxt = x @ x^T, split precision, triangle blocks ----------------
__global__ __launch_bounds__(256) void k_xxt(const unsigned short* __restrict__ xhi,
        const unsigned short* __restrict__ xlo, float* __restrict__ xxt){
  __shared__ char lds[32768];
  char* Als = lds; char* Bls = lds + 16384;
  int lin = blockIdx.x;                       // 1280 blocks
  int sz  = (lin&7)*160 + (lin>>3);
  int b = sz/10, sub = sz - b*10;
  unsigned mtp = (3u<<18)|(2u<<16)|(2u<<14)|(1u<<12)|(1u<<10)|(1u<<8)|(0u<<6)|(0u<<4)|(0u<<2)|0u;
  unsigned ntp = (3u<<18)|(3u<<16)|(2u<<14)|(3u<<12)|(2u<<10)|(1u<<8)|(3u<<6)|(2u<<4)|(1u<<2)|0u;
  int mt = (mtp>>(2*sub))&3, nt = (ntp>>(2*sub))&3;
  int c0 = mt*128, d0 = nt*128;
  int t = threadIdx.x, lane = t&63, wid = t>>6, wm = wid&1, wn = wid>>1;
  int fq = lane>>4, fr = lane&15;
  f32x4 acc[4][4] = {};
  for (int it=0; it<12; ++it){
    int seg = it>>2, kk0 = (it&3)*64;
    const unsigned short* As = (seg<2) ? xhi : xlo;
    const unsigned short* Bs = (seg==1) ? xlo : xhi;
    __syncthreads();
    #pragma unroll
    for (int r=0;r<4;++r){
      int L = r*256 + t;
      int row = L>>3, cs = ((L&7)^(row&7))*8;
      gl16(As + ((size_t)b*512 + c0 + row)*256 + kk0 + cs, Als + L*16);
      gl16(Bs + ((size_t)b*512 + d0 + row)*256 + kk0 + cs, Bls + L*16);
    }
    __syncthreads();
    #pragma unroll
    for (int ks=0; ks<2; ++ks){
      int kb = ks*64 + fq*16;
      bf16x8 af[4];
      #pragma unroll
      for (int m=0;m<4;++m){
        int row = wm*64 + m*16 + fr;
        af[m] = *(const bf16x8*)(Als + row*128 + (kb ^ ((row&7)<<4)));
      }
      #pragma unroll
      for (int n=0;n<4;++n){
        int row = wn*64 + n*16 + fr;
        bf16x8 bff = *(const bf16x8*)(Bls + row*128 + (kb ^ ((row&7)<<4)));
        #pragma unroll
        for (int m=0;m<4;++m)
          acc[m][n] = __builtin_amdgcn_mfma_f32_16x16x32_bf16(af[m], bff, acc[m][n],0,0,0);
      }
    }
  }
  for (int m=0;m<4;++m){
    int cb = c0 + wm*64 + m*16 + fq*4;
    for (int n=0;n<4;++n){
      int d = d0 + wn*64 + n*16 + fr;
      *(float4*)(xxt + ((size_t)b*512 + d)*512 + cb) = *(float4*)&acc[m][n];
    }
  }
  if (mt != nt){
    for (int m=0;m<4;++m){
      int cb = c0 + wm*64 + m*16 + fq*4;
      for (int n=0;n<4;++n){
        int d = d0 + wn*64 + n*16 + fr;
        for (int jj=0;jj<4;++jj)
          xxt[((size_t)b*512 + cb + jj)*512 + d] = acc[m][n][jj];
      }
    }
  }
}

// ---------------- softmax(-xxt) rows -> a (bf16) ----------------
__global__ __launch_bounds__(256) void k_softmax(const float* __restrict__ xxt, unsigned short* __restrict__ amat){
  int row = blockIdx.x*4 + (threadIdx.x>>6);
  int lane = threadIdx.x & 63;
  const float* src = xxt + (size_t)row*512 + lane*8;
  float4 v0 = *(const float4*)src;
  float4 v1 = *(const float4*)(src+4);
  float mn = fminf(fminf(fminf(v0.x,v0.y),fminf(v0.z,v0.w)),
                   fminf(fminf(v1.x,v1.y),fminf(v1.z,v1.w)));
  for (int m=32; m; m>>=1) mn = fminf(mn, __shfl_xor(mn, m, 64));
  float e[8];
  e[0]=__expf(mn-v0.x); e[1]=__expf(mn-v0.y); e[2]=__expf(mn-v0.z); e[3]=__expf(mn-v0.w);
  e[4]=__expf(mn-v1.x); e[5]=__expf(mn-v1.y); e[6]=__expf(mn-v1.z); e[7]=__expf(mn-v1.w);
  float s = e[0]+e[1]+e[2]+e[3]+e[4]+e[5]+e[6]+e[7];
  for (int m=32; m; m>>=1) s += __shfl_xor(s, m, 64);
  float inv = 1.f/s;
  short4v p0, p1;
  for (int q=0;q<4;++q) p0[q] = (short)f2bf(e[q]*inv);
  for (int q=0;q<4;++q) p1[q] = (short)f2bf(e[4+q]*inv);
  unsigned short* dst = amat + (size_t)row*512 + lane*8;
  *(short4v*)dst = p0;
  *(short4v*)(dst+4) = p1;
}

// ---------------- PV: y = a @ x -> ypad [b][ci0b 8][prow 256][cio 64] ----------------
__global__ __launch_bounds__(256) void k_pv(const unsigned short* __restrict__ amat,
        const unsigned short* __restrict__ xT, unsigned short* __restrict__ ypad){
  __shared__ char lds[30720];
  char* Als = lds; char* Bls = lds + 16384;
  int lin = blockIdx.x, per = gridDim.x>>3;
  int sz  = (lin&7)*per + (lin>>3);
  int b = sz>>3, sub = sz&7, mt = sub>>1, nt = sub&1;
  int c0 = mt*128, n0 = nt*112;
  int t = threadIdx.x, lane = t&63, wid = t>>6;
  int fq = lane>>4, fr = lane&15;
  f32x4 acc[2][7] = {};
  for (int it=0; it<8; ++it){
    int k0 = it*64;
    __syncthreads();
    #pragma unroll
    for (int r=0;r<4;++r){
      int L = r*256 + t;
      int row = L>>3, cs = ((L&7)^(row&7))*8;
      gl16(amat + ((size_t)b*512 + c0 + row)*512 + k0 + cs, Als + L*16);
    }
    #pragma unroll
    for (int r=0;r<4;++r){
      int L = r*256 + t;
      if (L < 896){
        int row = L>>3, cs = ((L&7)^(row&7))*8;
        gl16(xT + ((size_t)b*224 + n0 + row)*512 + k0 + cs, Bls + L*16);
      }
    }
    __syncthreads();
    #pragma unroll
    for (int ks=0; ks<2; ++ks){
      int kb = ks*64 + fq*16;
      bf16x8 af[2];
      #pragma unroll
      for (int m=0;m<2;++m){
        int row = wid*32 + m*16 + fr;
        af[m] = *(const bf16x8*)(Als + row*128 + (kb ^ ((row&7)<<4)));
      }
      #pragma unroll
      for (int n=0;n<7;++n){
        int row = n*16 + fr;
        bf16x8 bff = *(const bf16x8*)(Bls + row*128 + (kb ^ ((row&7)<<4)));
        #pragma unroll
        for (int m=0;m<2;++m)
          acc[m][n] = __builtin_amdgcn_mfma_f32_16x16x32_bf16(af[m], bff, acc[m][n],0,0,0);
      }
    }
  }
  for (int m=0;m<2;++m){
    int cb = c0 + wid*32 + m*16 + fq*4;
    int ci0b = cb>>6, cio = cb&63;
    for (int n=0;n<7;++n){
      int p = n0 + n*16 + fr;
      if (p < 196){
        int hh = p/14, wwp = p - hh*14;
        int prow = (hh+1)*16 + (wwp+1);
        short4v pk;
        for (int j=0;j<4;++j) pk[j] = (short)f2bf(acc[m][n][j]);
        *(short4v*)(ypad + (((size_t)b*8 + ci0b)*256 + prow)*64 + cio) = pk;
      }
    }
  }
}

// ---------------- conv3 implicit GEMM + BN2 + ReLU + avgpool -> zbar (sum) ----------------
__global__ __launch_bounds__(512, 4) void k_conv3(const unsigned short* __restrict__ ypad,
        const unsigned short* __restrict__ w3c, const float* __restrict__ par,
        float* __restrict__ zbar){
  __shared__ char lds[65536];
  char* WIN = lds;                 // [256][64] bf16, swizzled
  char* AB0 = lds + 32768;
  char* AB1 = lds + 49152;
  int bx = blockIdx.x;             // 512 blocks
  int xcd = bx&7, jj2 = bx>>3;
  int b = xcd*16 + (jj2>>2), cot = jj2&3;
  int c0 = cot*128;
  int t = threadIdx.x, lane = t&63, w = t>>6;
  int wm = w>>1, wn = w&1;
  int fq = lane>>4, fr = lane&15;
  int frB = (fr<14) ? fr : 13;
  bool pok = (fr<14);
  f32x4 acc[2][7] = {};
  for (int ci0=0; ci0<8; ++ci0){
    const unsigned short* wsrc = ypad + ((size_t)(b*8 + ci0)*256)*64;
    #pragma unroll
    for (int r=0;r<4;++r){
      int L = r*512 + t;
      int row = L>>3, cs = ((L&7)^(row&7))*8;
      gl16(wsrc + row*64 + cs, WIN + L*16);
    }
    {
      const unsigned short* asrc = w3c + ((size_t)(ci0*9 + 0)*512 + c0)*64;
      #pragma unroll
      for (int r=0;r<2;++r){
        int L = r*512 + t;
        int row = L>>3, cs = ((L&7)^(row&7))*8;
        gl16(asrc + row*64 + cs, AB0 + L*16);
      }
    }
    __syncthreads();
    for (int tap=0; tap<9; ++tap){
      char* Acur = (tap&1) ? AB1 : AB0;
      char* Anxt = (tap&1) ? AB0 : AB1;
      if (tap < 8){
        const unsigned short* asrc = w3c + ((size_t)(ci0*9 + tap+1)*512 + c0)*64;
        #pragma unroll
        for (int r=0;r<2;++r){
          int L = r*512 + t;
          int row = L>>3, cs = ((L&7)^(row&7))*8;
          gl16(asrc + row*64 + cs, Anxt + L*16);
        }
      }
      int kh = tap/3, kw = tap - kh*3;
      bf16x8 ah[2][2];
      #pragma unroll
      for (int ks=0;ks<2;++ks)
        #pragma unroll
        for (int m=0;m<2;++m){
          int row = wm*32 + m*16 + fr;
          ah[ks][m] = *(const bf16x8*)(Acur + row*128 + (((ks*4+fq)^(row&7))<<4));
        }
      int col = frB + kw;
      __builtin_amdgcn_s_setprio(1);
      #pragma unroll
      for (int n=0;n<7;++n){
        int prow = (wn*7 + n + kh)*16 + col;
        #pragma unroll
        for (int ks=0;ks<2;++ks){
          bf16x8 bf = *(const bf16x8*)(WIN + prow*128 + (((ks*4+fq)^(prow&7))<<4));
          acc[0][n] = __builtin_amdgcn_mfma_f32_16x16x32_bf16(ah[ks][0], bf, acc[0][n],0,0,0);
          acc[1][n] = __builtin_amdgcn_mfma_f32_16x16x32_bf16(ah[ks][1], bf, acc[1][n],0,0,0);
        }
      }
      __builtin_amdgcn_s_setprio(0);
      __syncthreads();
    }
  }
  const float* s2 = par+1024; const float* t2 = par+1536;
  float ps[2][4];
  #pragma unroll
  for (int m=0;m<2;++m){
    int cb = c0 + wm*32 + m*16 + fq*4;
    #pragma unroll
    for (int j=0;j<4;++j){
      float sc = s2[cb+j], sh = t2[cb+j];
      float s = 0.f;
      #pragma unroll
      for (int n=0;n<7;++n)
        s += fmaxf(acc[m][n][j]*sc + sh, 0.f);
      ps[m][j] = pok ? s : 0.f;
    }
  }
  #pragma unroll
  for (int off=1; off<16; off<<=1)
    #pragma unroll
    for (int m=0;m<2;++m)
      #pragma unroll
      for (int j=0;j<4;++j)
        ps[m][j] += __shfl_xor(ps[m][j], off, 64);
  float* part = (float*)lds;
  if (fr == 0){
    #pragma unroll
    for (int m=0;m<2;++m)
      #pragma unroll
      for (int j=0;j<4;++j)
        part[wn*128 + wm*32 + m*16 + fq*4 + j] = ps[m][j];
  }
  __syncthreads();
  if (t < 128)
    zbar[(size_t)b*512 + c0 + t] = part[t] + part[128 + t];
}

// ---------------- fc1(relu) + fc2 ----------------
__global__ __launch_bounds__(256) void k_fc(const float* __restrict__ zbar,
        const float* __restrict__ fc1T, const float* __restrict__ fc1b,
        const float* __restrict__ fc2T, const float* __restrict__ fc2b,
        float* __restrict__ out){
  __shared__ float zb[512];
  __shared__ float hl[200];
  int b = blockIdx.x, t = threadIdx.x;
  zb[t]     = zbar[(size_t)b*512 + t]       * (1.f/196.f);
  zb[t+256] = zbar[(size_t)b*512 + t + 256] * (1.f/196.f);
  __syncthreads();
  if (t < 200){
    float acc = fc1b[t];
    for (int k=0;k<512;++k) acc += zb[k]*fc1T[k*200+t];
    hl[t] = fmaxf(acc, 0.f);
  }
  __syncthreads();
  if (t < 200){
    float acc = fc2b[t];
    for (int k=0;k<200;++k) acc += hl[k]*fc2T[k*200+t];
    out[(size_t)b*200 + t] = acc;
  }
}

extern "C" void kernel_launch(void* const* d_in, const int* in_sizes, int n_in,
                              void* d_out, int out_size, void* d_ws, size_t ws_size,
                              hipStream_t stream) {
  const float* feature  = (const float*)d_in[0];
  const float* w_reduce = (const float*)d_in[1];
  const float* b_reduce = (const float*)d_in[2];
  const float* g1  = (const float*)d_in[3];
  const float* be1 = (const float*)d_in[4];
  const float* m1  = (const float*)d_in[5];
  const float* v1  = (const float*)d_in[6];
  const float* w3  = (const float*)d_in[7];
  const float* b3  = (const float*)d_in[8];
  const float* g2  = (const float*)d_in[9];
  const float* be2 = (const float*)d_in[10];
  const float* m2  = (const float*)d_in[11];
  const float* v2  = (const float*)d_in[12];
  const float* fc1w = (const float*)d_in[13];
  const float* fc1b = (const float*)d_in[14];
  const float* fc2w = (const float*)d_in[15];
  const float* fc2b = (const float*)d_in[16];

  char* ws = (char*)d_ws;
  unsigned short* fhi  = (unsigned short*)(ws + O_FHI);
  unsigned short* flo  = (unsigned short*)(ws + O_FLO);
  float*          xxt  = (float*)(ws + O_FHI);      // aliases fhi (dead after conv1)
  unsigned short* xhi  = (unsigned short*)(ws + O_XHI);
  unsigned short* xlo  = (unsigned short*)(ws + O_XLO);
  unsigned short* ypad = (unsigned short*)(ws + O_XLO);  // aliases xlo (dead after xxt)
  unsigned short* xT   = (unsigned short*)(ws + O_XT);
  unsigned short* amat = (unsigned short*)(ws + O_AMAT);
  unsigned short* wh   = (unsigned short*)(ws + O_WH);
  unsigned short* wl   = (unsigned short*)(ws + O_WL);
  unsigned short* w3c  = (unsigned short*)(ws + O_W3B);
  float* par  = (float*)(ws + O_PAR);
  float* fc1T = (float*)(ws + O_FC1T);
  float* fc2T = (float*)(ws + O_FC2T);
  float* zbar = (float*)(ws + O_ZBAR);

  k_params<<<2, 256, 0, stream>>>(b_reduce, g1, be1, m1, v1, b3, g2, be2, m2, v2, par);
  k_wrhl<<<dim3(8,512), 256, 0, stream>>>(w_reduce, wh, wl);
  k_w3c<<<dim3(18,512), 256, 0, stream>>>(w3, w3c);
  k_fc1t<<<400, 256, 0, stream>>>(fc1w, fc1T);
  k_fc2t<<<157, 256, 0, stream>>>(fc2w, fc2T);
  k_zeropad<<<256, 256, 0, stream>>>(xhi, xlo);

  k_featT<<<dim3(7,32,128), 256, 0, stream>>>(feature, fhi, flo);
  k_conv1<<<784, 256, 0, stream>>>(fhi, flo, wh, wl, par, xhi, xlo, xT);

  k_xxt<<<1280, 256, 0, stream>>>(xhi, xlo, xxt);
  k_softmax<<<16384, 256, 0, stream>>>(xxt, amat);

  k_zeroyb<<<1024, 256, 0, stream>>>(ypad);        // xlo dead; ypad borders -> 0
  k_pv<<<1024, 256, 0, stream>>>(amat, xT, ypad);
  k_conv3<<<512, 512, 0, stream>>>(ypad, w3c, par, zbar);
  k_fc<<<128, 256, 0, stream>>>(zbar, fc1T, fc1b, fc2T, fc2b, (float*)d_out);
}

// Round 5
// 605.368 us; speedup vs baseline: 1.1334x; 1.1334x over previous
//
#include <hip/hip_runtime.h>

typedef __attribute__((ext_vector_type(8))) short bf16x8;
typedef __attribute__((ext_vector_type(4))) float f32x4;
typedef __attribute__((ext_vector_type(4))) short short4v;

__device__ __forceinline__ unsigned short f2bf(float x){
  unsigned u = __float_as_uint(x);
  return (unsigned short)((u + 0x7FFFu + ((u>>16)&1u)) >> 16);
}
__device__ __forceinline__ float bf2f(unsigned short b){
  return __uint_as_float(((unsigned)b)<<16);
}

typedef const __attribute__((address_space(1))) void* gas_t;
typedef __attribute__((address_space(3))) void* las_t;
__device__ __forceinline__ void gl16(const void* g, void* l){
  __builtin_amdgcn_global_load_lds((gas_t)g, (las_t)l, 16, 0, 0);
}

// ---------------- workspace layout (bytes), ws_size ~784 MiB ----------------
static constexpr size_t O_FHI  = 0;              // fhi bf16 [25088][2048] 102760448 (later xxt f32 134217728)
static constexpr size_t O_FLO  = 102760448;      // flo bf16 [25088][2048] 102760448
static constexpr size_t O_XHI  = 205520896;      // x_hi bf16 [128][512][256] 33554432
static constexpr size_t O_XLO  = 239075328;      // x_lo bf16 (later ypad [b][8][256][64]) 33554432
static constexpr size_t O_XT   = 272629760;      // xT bf16 [128][224][512] 29360128
static constexpr size_t O_AMAT = 301989888;      // a bf16 [128][512][512] 67108864
static constexpr size_t O_WH   = 369098752;      // wh bf16 [512][2048] 2097152
static constexpr size_t O_WL   = 371195904;      // wl
static constexpr size_t O_W3B  = 373293056;      // w3c bf16 [8][9][512][64] 4718592
static constexpr size_t O_PAR  = 378011648;      // s1,t1,s2,t2
static constexpr size_t O_FC1T = 378019840;      // fc1T f32 [512][200]
static constexpr size_t O_FC2T = 378429440;      // fc2T f32 [200][200]
static constexpr size_t O_ZBAR = 378589440;      // zbar f32 [128][512] (sum)

// ---------------- prep kernels ----------------
__global__ void k_params(const float* br, const float* g1, const float* be1, const float* m1, const float* v1,
                         const float* b3, const float* g2, const float* be2, const float* m2, const float* v2,
                         float* par){
  int c = blockIdx.x*256 + threadIdx.x;
  if (c >= 512) return;
  float s1 = g1[c] * rsqrtf(v1[c] + 1e-5f);
  par[c] = s1;
  par[512+c] = (br[c]-m1[c])*s1 + be1[c];
  float s2 = g2[c] * rsqrtf(v2[c] + 1e-5f);
  par[1024+c] = s2;
  par[1536+c] = (b3[c]-m2[c])*s2 + be2[c];
}

__global__ void k_wrhl(const float* wr, unsigned short* wh, unsigned short* wl){
  int k = blockIdx.x*256 + threadIdx.x;
  int c = blockIdx.y;
  float v = wr[(size_t)c*2048 + k];
  unsigned short h = f2bf(v);
  wh[(size_t)c*2048 + k] = h;
  wl[(size_t)c*2048 + k] = f2bf(v - bf2f(h));
}

// w3c[ci0b][tap][co][cio] = bf16(w3[co][ci0b*64+cio][tap])
__global__ void k_w3c(const float* w3, unsigned short* w3c){
  int k = blockIdx.x*256 + threadIdx.x;     // < 4608
  int co = blockIdx.y;
  int ci0b = k/576; int r2 = k - ci0b*576;
  int tap = r2>>6;  int cio = r2&63;
  w3c[(((size_t)ci0b*9 + tap)*512 + co)*64 + cio] =
      f2bf(w3[((size_t)co*512 + ci0b*64 + cio)*9 + tap]);
}

__global__ void k_fc1t(const float* w, float* wt){
  int i = blockIdx.x*256 + threadIdx.x;
  int k = i/200, j = i - k*200;
  wt[i] = w[j*512 + k];
}
__global__ void k_fc2t(const float* w, float* wt){
  int i = blockIdx.x*256 + threadIdx.x;
  if (i >= 200*200) return;
  int k = i/200, j = i - k*200;
  wt[i] = w[j*200 + k];
}

// zero cols [192,256) of xhi/xlo rows [128*512] (conv1 later overwrites 192..195)
__global__ __launch_bounds__(256) void k_zeropad(unsigned short* xhi, unsigned short* xlo){
  int rr = blockIdx.x*256 + threadIdx.x;     // 65536 rows
  float4 z = {0.f,0.f,0.f,0.f};
  float4* a = (float4*)(xhi + (size_t)rr*256 + 192);
  float4* b = (float4*)(xlo + (size_t)rr*256 + 192);
  #pragma unroll
  for (int j=0;j<8;++j){ a[j] = z; b[j] = z; }
}

// zero the 60 border rows of each ypad[b][cib][256][64] tile
__global__ __launch_bounds__(256) void k_zeroyb(unsigned short* ypad){
  int tile = blockIdx.x;                     // 1024 = b*8+cib
  int r = threadIdx.x;
  if (r >= 256) return;
  int hi = r>>4, lo = r&15;
  bool pad = (hi==0)||(hi==15)||(lo==0)||(lo==15);
  if (!pad) return;
  float4 z = {0.f,0.f,0.f,0.f};
  float4* p = (float4*)(ypad + ((size_t)tile*256 + r)*64);
  #pragma unroll
  for (int j=0;j<8;++j) p[j] = z;
}

// transpose+split feature -> dense fhi/flo bf16 [b*196+p][2048]
__global__ __launch_bounds__(256) void k_featT(const float* __restrict__ feat,
        unsigned short* __restrict__ fhi, unsigned short* __restrict__ flo){
  __shared__ float tile[64][33];
  int b = blockIdx.z;
  int ci0 = blockIdx.y*64, p0 = blockIdx.x*32;
  int t = threadIdx.x;
  int j = t & 31, i0 = t >> 5;
  for (int rep=0; rep<8; ++rep){
    int i = rep*8 + i0;
    int p = p0 + j;
    tile[i][j] = (p<196) ? feat[((size_t)b*2048 + ci0 + i)*196 + p] : 0.f;
  }
  __syncthreads();
  int ii = t & 63, jj0 = t >> 6;
  for (int rep=0; rep<8; ++rep){
    int jj = rep*4 + jj0;
    int p = p0 + jj;
    if (p < 196){
      float v = tile[ii][jj];
      unsigned short h = f2bf(v);
      size_t o = ((size_t)b*196 + p)*2048 + ci0 + ii;
      fhi[o] = h;
      flo[o] = f2bf(v - bf2f(h));
    }
  }
}

// ---------------- conv1 dense GEMM: [512co] x [25088 g], 4-buffer K-chunks ----------------
// Per K=64 chunk: stage {wh,wl,fh,fl} (64 KB), then 3 seg-products (96 MFMA/wave)
// between one barrier pair. LDS 64 KB -> exactly 2 blocks/CU resident.
__global__ __launch_bounds__(256) void k_conv1(
    const unsigned short* __restrict__ fhi, const unsigned short* __restrict__ flo,
    const unsigned short* __restrict__ wh,  const unsigned short* __restrict__ wl,
    const float* __restrict__ par,
    unsigned short* __restrict__ xhi, unsigned short* __restrict__ xlo,
    unsigned short* __restrict__ xT){
  __shared__ char lds[65536];
  char* WH = lds;
  char* WL = lds + 16384;
  char* FH = lds + 32768;
  char* FL = lds + 49152;
  int lin = blockIdx.x;                       // 784 blocks
  int sz  = (lin&7)*98 + (lin>>3);            // XCD swizzle (784%8==0)
  int mt = sz&3;                              // co tile: 4 consecutive share B panel
  int gt = sz>>2;                             // 0..195
  int c0 = mt*128;
  size_t g0 = (size_t)gt*128;
  int t = threadIdx.x, lane = t&63, wid = t>>6, wm = wid&1, wn = wid>>1;
  int fq = lane>>4, fr = lane&15;
  f32x4 acc[4][4] = {};
  for (int it=0; it<32; ++it){
    int kk0 = it*64;
    __syncthreads();
    #pragma unroll
    for (int r=0;r<4;++r){
      int L = r*256 + t;
      int row = L>>3, cs = ((L&7)^(row&7))*8;
      size_t ga = (size_t)(c0+row)*2048 + kk0 + cs;
      size_t gb = (g0+row)*2048 + kk0 + cs;
      gl16(wh + ga, WH + L*16);
      gl16(wl + ga, WL + L*16);
      gl16(fhi + gb, FH + L*16);
      gl16(flo + gb, FL + L*16);
    }
    __syncthreads();
    #pragma unroll
    for (int seg=0; seg<3; ++seg){
      const char* Abuf = (seg==2) ? WL : WH;
      const char* Bbuf = (seg==1) ? FL : FH;
      #pragma unroll
      for (int ks=0; ks<2; ++ks){
        int kb = ks*64 + fq*16;
        bf16x8 af[4];
        #pragma unroll
        for (int m=0;m<4;++m){
          int row = wm*64 + m*16 + fr;
          af[m] = *(const bf16x8*)(Abuf + row*128 + (kb ^ ((row&7)<<4)));
        }
        #pragma unroll
        for (int n=0;n<4;++n){
          int row = wn*64 + n*16 + fr;
          bf16x8 bff = *(const bf16x8*)(Bbuf + row*128 + (kb ^ ((row&7)<<4)));
          #pragma unroll
          for (int m=0;m<4;++m)
            acc[m][n] = __builtin_amdgcn_mfma_f32_16x16x32_bf16(af[m], bff, acc[m][n],0,0,0);
        }
      }
    }
  }
  const float* s1 = par; const float* t1 = par+512;
  for (int m=0;m<4;++m){
    int cb = c0 + wm*64 + m*16 + fq*4;
    float sc[4], sh[4];
    for (int j=0;j<4;++j){ sc[j]=s1[cb+j]; sh[j]=t1[cb+j]; }
    for (int n=0;n<4;++n){
      int gg = (int)g0 + wn*64 + n*16 + fr;
      int b = gg/196, p = gg - b*196;
      unsigned short hs[4];
      for (int j=0;j<4;++j){
        float v = fmaxf(acc[m][n][j]*sc[j]+sh[j], 0.f);
        unsigned short h = f2bf(v);
        hs[j] = h;
        size_t ic = (size_t)b*512 + cb + j;
        xhi[ic*256 + p] = h;
        xlo[ic*256 + p] = f2bf(v - bf2f(h));
      }
      *(short4v*)(xT + ((size_t)b*224 + p)*512 + cb) = *(short4v*)hs;
    }
  }
}

// ---------------- xxt = x @ x^T, split precision, triangle blocks ----------------
__global__ __launch_bounds__(256) void k_xxt(const unsigned short* __restrict__ xhi,
        const unsigned short* __restrict__ xlo, float* __restrict__ xxt){
  __shared__ char lds[32768];
  char* Als = lds; char* Bls = lds + 16384;
  int lin = blockIdx.x;                       // 1280 blocks
  int sz  = (lin&7)*160 + (lin>>3);
  int b = sz/10, sub = sz - b*10;
  unsigned mtp = (3u<<18)|(2u<<16)|(2u<<14)|(1u<<12)|(1u<<10)|(1u<<8)|(0u<<6)|(0u<<4)|(0u<<2)|0u;
  unsigned ntp = (3u<<18)|(3u<<16)|(2u<<14)|(3u<<12)|(2u<<10)|(1u<<8)|(3u<<6)|(2u<<4)|(1u<<2)|0u;
  int mt = (mtp>>(2*sub))&3, nt = (ntp>>(2*sub))&3;
  int c0 = mt*128, d0 = nt*128;
  int t = threadIdx.x, lane = t&63, wid = t>>6, wm = wid&1, wn = wid>>1;
  int fq = lane>>4, fr = lane&15;
  f32x4 acc[4][4] = {};
  for (int it=0; it<12; ++it){
    int seg = it>>2, kk0 = (it&3)*64;
    const unsigned short* As = (seg<2) ? xhi : xlo;
    const unsigned short* Bs = (seg==1) ? xlo : xhi;
    __syncthreads();
    #pragma unroll
    for (int r=0;r<4;++r){
      int L = r*256 + t;
      int row = L>>3, cs = ((L&7)^(row&7))*8;
      gl16(As + ((size_t)b*512 + c0 + row)*256 + kk0 + cs, Als + L*16);
      gl16(Bs + ((size_t)b*512 + d0 + row)*256 + kk0 + cs, Bls + L*16);
    }
    __syncthreads();
    #pragma unroll
    for (int ks=0; ks<2; ++ks){
      int kb = ks*64 + fq*16;
      bf16x8 af[4];
      #pragma unroll
      for (int m=0;m<4;++m){
        int row = wm*64 + m*16 + fr;
        af[m] = *(const bf16x8*)(Als + row*128 + (kb ^ ((row&7)<<4)));
      }
      #pragma unroll
      for (int n=0;n<4;++n){
        int row = wn*64 + n*16 + fr;
        bf16x8 bff = *(const bf16x8*)(Bls + row*128 + (kb ^ ((row&7)<<4)));
        #pragma unroll
        for (int m=0;m<4;++m)
          acc[m][n] = __builtin_amdgcn_mfma_f32_16x16x32_bf16(af[m], bff, acc[m][n],0,0,0);
      }
    }
  }
  for (int m=0;m<4;++m){
    int cb = c0 + wm*64 + m*16 + fq*4;
    for (int n=0;n<4;++n){
      int d = d0 + wn*64 + n*16 + fr;
      *(float4*)(xxt + ((size_t)b*512 + d)*512 + cb) = *(float4*)&acc[m][n];
    }
  }
  if (mt != nt){
    for (int m=0;m<4;++m){
      int cb = c0 + wm*64 + m*16 + fq*4;
      for (int n=0;n<4;++n){
        int d = d0 + wn*64 + n*16 + fr;
        for (int jj=0;jj<4;++jj)
          xxt[((size_t)b*512 + cb + jj)*512 + d] = acc[m][n][jj];
      }
    }
  }
}

// ---------------- softmax(-xxt) rows -> a (bf16) ----------------
__global__ __launch_bounds__(256) void k_softmax(const float* __restrict__ xxt, unsigned short* __restrict__ amat){
  int row = blockIdx.x*4 + (threadIdx.x>>6);
  int lane = threadIdx.x & 63;
  const float* src = xxt + (size_t)row*512 + lane*8;
  float4 v0 = *(const float4*)src;
  float4 v1 = *(const float4*)(src+4);
  float mn = fminf(fminf(fminf(v0.x,v0.y),fminf(v0.z,v0.w)),
                   fminf(fminf(v1.x,v1.y),fminf(v1.z,v1.w)));
  for (int m=32; m; m>>=1) mn = fminf(mn, __shfl_xor(mn, m, 64));
  float e[8];
  e[0]=__expf(mn-v0.x); e[1]=__expf(mn-v0.y); e[2]=__expf(mn-v0.z); e[3]=__expf(mn-v0.w);
  e[4]=__expf(mn-v1.x); e[5]=__expf(mn-v1.y); e[6]=__expf(mn-v1.z); e[7]=__expf(mn-v1.w);
  float s = e[0]+e[1]+e[2]+e[3]+e[4]+e[5]+e[6]+e[7];
  for (int m=32; m; m>>=1) s += __shfl_xor(s, m, 64);
  float inv = 1.f/s;
  short4v p0, p1;
  for (int q=0;q<4;++q) p0[q] = (short)f2bf(e[q]*inv);
  for (int q=0;q<4;++q) p1[q] = (short)f2bf(e[4+q]*inv);
  unsigned short* dst = amat + (size_t)row*512 + lane*8;
  *(short4v*)dst = p0;
  *(short4v*)(dst+4) = p1;
}

// ---------------- PV: y = a @ x -> ypad [b][ci0b 8][prow 256][cio 64] ----------------
__global__ __launch_bounds__(256) void k_pv(const unsigned short* __restrict__ amat,
        const unsigned short* __restrict__ xT, unsigned short* __restrict__ ypad){
  __shared__ char lds[30720];
  char* Als = lds; char* Bls = lds + 16384;
  int lin = blockIdx.x, per = gridDim.x>>3;
  int sz  = (lin&7)*per + (lin>>3);
  int b = sz>>3, sub = sz&7, mt = sub>>1, nt = sub&1;
  int c0 = mt*128, n0 = nt*112;
  int t = threadIdx.x, lane = t&63, wid = t>>6;
  int fq = lane>>4, fr = lane&15;
  f32x4 acc[2][7] = {};
  for (int it=0; it<8; ++it){
    int k0 = it*64;
    __syncthreads();
    #pragma unroll
    for (int r=0;r<4;++r){
      int L = r*256 + t;
      int row = L>>3, cs = ((L&7)^(row&7))*8;
      gl16(amat + ((size_t)b*512 + c0 + row)*512 + k0 + cs, Als + L*16);
    }
    #pragma unroll
    for (int r=0;r<4;++r){
      int L = r*256 + t;
      if (L < 896){
        int row = L>>3, cs = ((L&7)^(row&7))*8;
        gl16(xT + ((size_t)b*224 + n0 + row)*512 + k0 + cs, Bls + L*16);
      }
    }
    __syncthreads();
    #pragma unroll
    for (int ks=0; ks<2; ++ks){
      int kb = ks*64 + fq*16;
      bf16x8 af[2];
      #pragma unroll
      for (int m=0;m<2;++m){
        int row = wid*32 + m*16 + fr;
        af[m] = *(const bf16x8*)(Als + row*128 + (kb ^ ((row&7)<<4)));
      }
      #pragma unroll
      for (int n=0;n<7;++n){
        int row = n*16 + fr;
        bf16x8 bff = *(const bf16x8*)(Bls + row*128 + (kb ^ ((row&7)<<4)));
        #pragma unroll
        for (int m=0;m<2;++m)
          acc[m][n] = __builtin_amdgcn_mfma_f32_16x16x32_bf16(af[m], bff, acc[m][n],0,0,0);
      }
    }
  }
  for (int m=0;m<2;++m){
    int cb = c0 + wid*32 + m*16 + fq*4;
    int ci0b = cb>>6, cio = cb&63;
    for (int n=0;n<7;++n){
      int p = n0 + n*16 + fr;
      if (p < 196){
        int hh = p/14, wwp = p - hh*14;
        int prow = (hh+1)*16 + (wwp+1);
        short4v pk;
        for (int j=0;j<4;++j) pk[j] = (short)f2bf(acc[m][n][j]);
        *(short4v*)(ypad + (((size_t)b*8 + ci0b)*256 + prow)*64 + cio) = pk;
      }
    }
  }
}

// ---------------- conv3 implicit GEMM + BN2 + ReLU + avgpool -> zbar (sum) ----------------
__global__ __launch_bounds__(512, 4) void k_conv3(const unsigned short* __restrict__ ypad,
        const unsigned short* __restrict__ w3c, const float* __restrict__ par,
        float* __restrict__ zbar){
  __shared__ char lds[65536];
  char* WIN = lds;                 // [256][64] bf16, swizzled
  char* AB0 = lds + 32768;
  char* AB1 = lds + 49152;
  int bx = blockIdx.x;             // 512 blocks
  int xcd = bx&7, jj2 = bx>>3;
  int b = xcd*16 + (jj2>>2), cot = jj2&3;
  int c0 = cot*128;
  int t = threadIdx.x, lane = t&63, w = t>>6;
  int wm = w>>1, wn = w&1;
  int fq = lane>>4, fr = lane&15;
  int frB = (fr<14) ? fr : 13;
  bool pok = (fr<14);
  f32x4 acc[2][7] = {};
  for (int ci0=0; ci0<8; ++ci0){
    const unsigned short* wsrc = ypad + ((size_t)(b*8 + ci0)*256)*64;
    #pragma unroll
    for (int r=0;r<4;++r){
      int L = r*512 + t;
      int row = L>>3, cs = ((L&7)^(row&7))*8;
      gl16(wsrc + row*64 + cs, WIN + L*16);
    }
    {
      const unsigned short* asrc = w3c + ((size_t)(ci0*9 + 0)*512 + c0)*64;
      #pragma unroll
      for (int r=0;r<2;++r){
        int L = r*512 + t;
        int row = L>>3, cs = ((L&7)^(row&7))*8;
        gl16(asrc + row*64 + cs, AB0 + L*16);
      }
    }
    __syncthreads();
    for (int tap=0; tap<9; ++tap){
      char* Acur = (tap&1) ? AB1 : AB0;
      char* Anxt = (tap&1) ? AB0 : AB1;
      if (tap < 8){
        const unsigned short* asrc = w3c + ((size_t)(ci0*9 + tap+1)*512 + c0)*64;
        #pragma unroll
        for (int r=0;r<2;++r){
          int L = r*512 + t;
          int row = L>>3, cs = ((L&7)^(row&7))*8;
          gl16(asrc + row*64 + cs, Anxt + L*16);
        }
      }
      int kh = tap/3, kw = tap - kh*3;
      bf16x8 ah[2][2];
      #pragma unroll
      for (int ks=0;ks<2;++ks)
        #pragma unroll
        for (int m=0;m<2;++m){
          int row = wm*32 + m*16 + fr;
          ah[ks][m] = *(const bf16x8*)(Acur + row*128 + (((ks*4+fq)^(row&7))<<4));
        }
      int col = frB + kw;
      __builtin_amdgcn_s_setprio(1);
      #pragma unroll
      for (int n=0;n<7;++n){
        int prow = (wn*7 + n + kh)*16 + col;
        #pragma unroll
        for (int ks=0;ks<2;++ks){
          bf16x8 bf = *(const bf16x8*)(WIN + prow*128 + (((ks*4+fq)^(prow&7))<<4));
          acc[0][n] = __builtin_amdgcn_mfma_f32_16x16x32_bf16(ah[ks][0], bf, acc[0][n],0,0,0);
          acc[1][n] = __builtin_amdgcn_mfma_f32_16x16x32_bf16(ah[ks][1], bf, acc[1][n],0,0,0);
        }
      }
      __builtin_amdgcn_s_setprio(0);
      __syncthreads();
    }
  }
  const float* s2 = par+1024; const float* t2 = par+1536;
  float ps[2][4];
  #pragma unroll
  for (int m=0;m<2;++m){
    int cb = c0 + wm*32 + m*16 + fq*4;
    #pragma unroll
    for (int j=0;j<4;++j){
      float sc = s2[cb+j], sh = t2[cb+j];
      float s = 0.f;
      #pragma unroll
      for (int n=0;n<7;++n)
        s += fmaxf(acc[m][n][j]*sc + sh, 0.f);
      ps[m][j] = pok ? s : 0.f;
    }
  }
  #pragma unroll
  for (int off=1; off<16; off<<=1)
    #pragma unroll
    for (int m=0;m<2;++m)
      #pragma unroll
      for (int j=0;j<4;++j)
        ps[m][j] += __shfl_xor(ps[m][j], off, 64);
  float* part = (float*)lds;
  if (fr == 0){
    #pragma unroll
    for (int m=0;m<2;++m)
      #pragma unroll
      for (int j=0;j<4;++j)
        part[wn*128 + wm*32 + m*16 + fq*4 + j] = ps[m][j];
  }
  __syncthreads();
  if (t < 128)
    zbar[(size_t)b*512 + c0 + t] = part[t] + part[128 + t];
}

// ---------------- fc1(relu) + fc2 ----------------
__global__ __launch_bounds__(256) void k_fc(const float* __restrict__ zbar,
        const float* __restrict__ fc1T, const float* __restrict__ fc1b,
        const float* __restrict__ fc2T, const float* __restrict__ fc2b,
        float* __restrict__ out){
  __shared__ float zb[512];
  __shared__ float hl[200];
  int b = blockIdx.x, t = threadIdx.x;
  zb[t]     = zbar[(size_t)b*512 + t]       * (1.f/196.f);
  zb[t+256] = zbar[(size_t)b*512 + t + 256] * (1.f/196.f);
  __syncthreads();
  if (t < 200){
    float acc = fc1b[t];
    for (int k=0;k<512;++k) acc += zb[k]*fc1T[k*200+t];
    hl[t] = fmaxf(acc, 0.f);
  }
  __syncthreads();
  if (t < 200){
    float acc = fc2b[t];
    for (int k=0;k<200;++k) acc += hl[k]*fc2T[k*200+t];
    out[(size_t)b*200 + t] = acc;
  }
}

extern "C" void kernel_launch(void* const* d_in, const int* in_sizes, int n_in,
                              void* d_out, int out_size, void* d_ws, size_t ws_size,
                              hipStream_t stream) {
  const float* feature  = (const float*)d_in[0];
  const float* w_reduce = (const float*)d_in[1];
  const float* b_reduce = (const float*)d_in[2];
  const float* g1  = (const float*)d_in[3];
  const float* be1 = (const float*)d_in[4];
  const float* m1  = (const float*)d_in[5];
  const float* v1  = (const float*)d_in[6];
  const float* w3  = (const float*)d_in[7];
  const float* b3  = (const float*)d_in[8];
  const float* g2  = (const float*)d_in[9];
  const float* be2 = (const float*)d_in[10];
  const float* m2  = (const float*)d_in[11];
  const float* v2  = (const float*)d_in[12];
  const float* fc1w = (const float*)d_in[13];
  const float* fc1b = (const float*)d_in[14];
  const float* fc2w = (const float*)d_in[15];
  const float* fc2b = (const float*)d_in[16];

  char* ws = (char*)d_ws;
  unsigned short* fhi  = (unsigned short*)(ws + O_FHI);
  unsigned short* flo  = (unsigned short*)(ws + O_FLO);
  float*          xxt  = (float*)(ws + O_FHI);      // aliases fhi (dead after conv1)
  unsigned short* xhi  = (unsigned short*)(ws + O_XHI);
  unsigned short* xlo  = (unsigned short*)(ws + O_XLO);
  unsigned short* ypad = (unsigned short*)(ws + O_XLO);  // aliases xlo (dead after xxt)
  unsigned short* xT   = (unsigned short*)(ws + O_XT);
  unsigned short* amat = (unsigned short*)(ws + O_AMAT);
  unsigned short* wh   = (unsigned short*)(ws + O_WH);
  unsigned short* wl   = (unsigned short*)(ws + O_WL);
  unsigned short* w3c  = (unsigned short*)(ws + O_W3B);
  float* par  = (float*)(ws + O_PAR);
  float* fc1T = (float*)(ws + O_FC1T);
  float* fc2T = (float*)(ws + O_FC2T);
  float* zbar = (float*)(ws + O_ZBAR);

  k_params<<<2, 256, 0, stream>>>(b_reduce, g1, be1, m1, v1, b3, g2, be2, m2, v2, par);
  k_wrhl<<<dim3(8,512), 256, 0, stream>>>(w_reduce, wh, wl);
  k_w3c<<<dim3(18,512), 256, 0, stream>>>(w3, w3c);
  k_fc1t<<<400, 256, 0, stream>>>(fc1w, fc1T);
  k_fc2t<<<157, 256, 0, stream>>>(fc2w, fc2T);
  k_zeropad<<<256, 256, 0, stream>>>(xhi, xlo);

  k_featT<<<dim3(7,32,128), 256, 0, stream>>>(feature, fhi, flo);
  k_conv1<<<784, 256, 0, stream>>>(fhi, flo, wh, wl, par, xhi, xlo, xT);

  k_xxt<<<1280, 256, 0, stream>>>(xhi, xlo, xxt);
  k_softmax<<<16384, 256, 0, stream>>>(xxt, amat);

  k_zeroyb<<<1024, 256, 0, stream>>>(ypad);        // xlo dead; ypad borders -> 0
  k_pv<<<1024, 256, 0, stream>>>(amat, xT, ypad);
  k_conv3<<<512, 512, 0, stream>>>(ypad, w3c, par, zbar);
  k_fc<<<128, 256, 0, stream>>>(zbar, fc1T, fc1b, fc2T, fc2b, (float*)d_out);
}

// Round 6
// 598.764 us; speedup vs baseline: 1.1459x; 1.0110x over previous
//
#include <hip/hip_runtime.h>

typedef __attribute__((ext_vector_type(8))) short bf16x8;
typedef __attribute__((ext_vector_type(4))) float f32x4;
typedef __attribute__((ext_vector_type(4))) short short4v;

__device__ __forceinline__ unsigned short f2bf(float x){
  unsigned u = __float_as_uint(x);
  return (unsigned short)((u + 0x7FFFu + ((u>>16)&1u)) >> 16);
}
__device__ __forceinline__ float bf2f(unsigned short b){
  return __uint_as_float(((unsigned)b)<<16);
}

typedef const __attribute__((address_space(1))) void* gas_t;
typedef __attribute__((address_space(3))) void* las_t;
__device__ __forceinline__ void gl16(const void* g, void* l){
  __builtin_amdgcn_global_load_lds((gas_t)g, (las_t)l, 16, 0, 0);
}

// ---------------- workspace layout (bytes), ws_size ~784 MiB ----------------
static constexpr size_t O_FHI  = 0;              // fhi bf16 [25088][2048] (later xxt f32)
static constexpr size_t O_FLO  = 102760448;      // flo bf16 [25088][2048]
static constexpr size_t O_XHI  = 205520896;      // x_hi bf16 [128][512][256]
static constexpr size_t O_XLO  = 239075328;      // x_lo bf16 (later ypad [b][8][256][64])
static constexpr size_t O_XT   = 272629760;      // xT bf16 [128][224][512]
static constexpr size_t O_AMAT = 301989888;      // a bf16 [128][512][512]
static constexpr size_t O_WH   = 369098752;      // wh bf16 [512][2048]
static constexpr size_t O_WL   = 371195904;      // wl
static constexpr size_t O_W3B  = 373293056;      // w3c bf16 [8][9][512][64]
static constexpr size_t O_PAR  = 378011648;      // s1,t1,s2,t2
static constexpr size_t O_FC1T = 378019840;      // fc1T f32 [512][200]
static constexpr size_t O_FC2T = 378429440;      // fc2T f32 [200][200]
static constexpr size_t O_ZBAR = 378589440;      // zbar f32 [128][512] (sum)

// ---------------- prep kernels ----------------
__global__ void k_params(const float* br, const float* g1, const float* be1, const float* m1, const float* v1,
                         const float* b3, const float* g2, const float* be2, const float* m2, const float* v2,
                         float* par){
  int c = blockIdx.x*256 + threadIdx.x;
  if (c >= 512) return;
  float s1 = g1[c] * rsqrtf(v1[c] + 1e-5f);
  par[c] = s1;
  par[512+c] = (br[c]-m1[c])*s1 + be1[c];
  float s2 = g2[c] * rsqrtf(v2[c] + 1e-5f);
  par[1024+c] = s2;
  par[1536+c] = (b3[c]-m2[c])*s2 + be2[c];
}

__global__ void k_wrhl(const float* wr, unsigned short* wh, unsigned short* wl){
  int k = blockIdx.x*256 + threadIdx.x;
  int c = blockIdx.y;
  float v = wr[(size_t)c*2048 + k];
  unsigned short h = f2bf(v);
  wh[(size_t)c*2048 + k] = h;
  wl[(size_t)c*2048 + k] = f2bf(v - bf2f(h));
}

// w3c[ci0b][tap][co][cio] = bf16(w3[co][ci0b*64+cio][tap])
__global__ void k_w3c(const float* w3, unsigned short* w3c){
  int k = blockIdx.x*256 + threadIdx.x;     // < 4608
  int co = blockIdx.y;
  int ci0b = k/576; int r2 = k - ci0b*576;
  int tap = r2>>6;  int cio = r2&63;
  w3c[(((size_t)ci0b*9 + tap)*512 + co)*64 + cio] =
      f2bf(w3[((size_t)co*512 + ci0b*64 + cio)*9 + tap]);
}

__global__ void k_fc1t(const float* w, float* wt){
  int i = blockIdx.x*256 + threadIdx.x;
  int k = i/200, j = i - k*200;
  wt[i] = w[j*512 + k];
}
__global__ void k_fc2t(const float* w, float* wt){
  int i = blockIdx.x*256 + threadIdx.x;
  if (i >= 200*200) return;
  int k = i/200, j = i - k*200;
  wt[i] = w[j*200 + k];
}

// zero cols [192,256) of xhi/xlo rows [128*512]
__global__ __launch_bounds__(256) void k_zeropad(unsigned short* xhi, unsigned short* xlo){
  int rr = blockIdx.x*256 + threadIdx.x;     // 65536 rows
  float4 z = {0.f,0.f,0.f,0.f};
  float4* a = (float4*)(xhi + (size_t)rr*256 + 192);
  float4* b = (float4*)(xlo + (size_t)rr*256 + 192);
  #pragma unroll
  for (int j=0;j<8;++j){ a[j] = z; b[j] = z; }
}

// zero the 60 border rows of each ypad[b][cib][256][64] tile
__global__ __launch_bounds__(256) void k_zeroyb(unsigned short* ypad){
  int tile = blockIdx.x;                     // 1024 = b*8+cib
  int r = threadIdx.x;
  if (r >= 256) return;
  int hi = r>>4, lo = r&15;
  bool pad = (hi==0)||(hi==15)||(lo==0)||(lo==15);
  if (!pad) return;
  float4 z = {0.f,0.f,0.f,0.f};
  float4* p = (float4*)(ypad + ((size_t)tile*256 + r)*64);
  #pragma unroll
  for (int j=0;j<8;++j) p[j] = z;
}

// transpose+split feature -> dense fhi/flo bf16 [b*196+p][2048]
__global__ __launch_bounds__(256) void k_featT(const float* __restrict__ feat,
        unsigned short* __restrict__ fhi, unsigned short* __restrict__ flo){
  __shared__ float tile[64][33];
  int b = blockIdx.z;
  int ci0 = blockIdx.y*64, p0 = blockIdx.x*32;
  int t = threadIdx.x;
  int j = t & 31, i0 = t >> 5;
  for (int rep=0; rep<8; ++rep){
    int i = rep*8 + i0;
    int p = p0 + j;
    tile[i][j] = (p<196) ? feat[((size_t)b*2048 + ci0 + i)*196 + p] : 0.f;
  }
  __syncthreads();
  int ii = t & 63, jj0 = t >> 6;
  for (int rep=0; rep<8; ++rep){
    int jj = rep*4 + jj0;
    int p = p0 + jj;
    if (p < 196){
      float v = tile[ii][jj];
      unsigned short h = f2bf(v);
      size_t o = ((size_t)b*196 + p)*2048 + ci0 + ii;
      fhi[o] = h;
      flo[o] = f2bf(v - bf2f(h));
    }
  }
}

// ---------------- conv1 dense GEMM, 2-phase pipelined (T3/T4 minimum template) ----------------
// K split into 64 half-chunks of 32; each half-chunk buffer = {wh,wl,fh,fl} x [128][32]bf16
// = 32 KB; double-buffered (64 KB) -> 2 blocks/CU. STAGE(next) issued before MFMA phase;
// raw s_barrier + one vmcnt(0) AFTER the MFMA cluster (loads land under compute).
__global__ __launch_bounds__(256) void k_conv1(
    const unsigned short* __restrict__ fhi, const unsigned short* __restrict__ flo,
    const unsigned short* __restrict__ wh,  const unsigned short* __restrict__ wl,
    const float* __restrict__ par,
    unsigned short* __restrict__ xhi, unsigned short* __restrict__ xlo,
    unsigned short* __restrict__ xT){
  __shared__ char lds[65536];
  char* BUF0 = lds;
  char* BUF1 = lds + 32768;
  int lin = blockIdx.x;                       // 784 blocks
  int sz  = (lin&7)*98 + (lin>>3);            // XCD swizzle (784%8==0)
  int mt = sz&3;                              // co tile: 4 consecutive share B panel (same XCD)
  int gt = sz>>2;                             // 0..195
  int c0 = mt*128;
  size_t g0 = (size_t)gt*128;
  int t = threadIdx.x, lane = t&63, wid = t>>6, wm = wid&1, wn = wid>>1;
  int fq = lane>>4, fr = lane&15;
  f32x4 acc[4][4] = {};

  // per-thread stage slots: 8 gl16 = 4 arrays x 2 slots
  // slot L2 = t + 256*(j&1); row = L2>>2; cslot = L2&3; swizzled source col
  auto STAGE = [&](int hc, char* buf){
    #pragma unroll
    for (int j=0;j<8;++j){
      int arr = j>>1;
      int L2 = t + ((j&1)<<8);
      int row = L2>>2;
      int cs = ((L2&3) ^ ((row>>1)&3))*8;       // element offset (bf16)
      const unsigned short* src;
      if (arr==0)      src = wh  + (size_t)(c0+row)*2048 + hc*32 + cs;
      else if (arr==1) src = wl  + (size_t)(c0+row)*2048 + hc*32 + cs;
      else if (arr==2) src = fhi + (g0+row)*2048 + hc*32 + cs;
      else             src = flo + (g0+row)*2048 + hc*32 + cs;
      gl16(src, buf + arr*8192 + L2*16);
    }
  };

  STAGE(0, BUF0);
  asm volatile("s_waitcnt vmcnt(0)" ::: "memory");
  __builtin_amdgcn_s_barrier();
  __builtin_amdgcn_sched_barrier(0);

  for (int it=0; it<64; ++it){
    char* cur = (it&1) ? BUF1 : BUF0;
    char* nxt = (it&1) ? BUF0 : BUF1;
    if (it < 63) STAGE(it+1, nxt);
    __builtin_amdgcn_s_setprio(1);
    #pragma unroll
    for (int seg=0; seg<3; ++seg){
      const char* Ab = cur + ((seg==2) ? 8192 : 0);
      const char* Bb = cur + ((seg==1) ? 24576 : 16384);
      bf16x8 af[4], bfr[4];
      #pragma unroll
      for (int m=0;m<4;++m){
        int row = wm*64 + m*16 + fr;
        af[m] = *(const bf16x8*)(Ab + row*64 + ((fq*16) ^ (((row>>1)&3)<<4)));
      }
      #pragma unroll
      for (int n=0;n<4;++n){
        int row = wn*64 + n*16 + fr;
        bfr[n] = *(const bf16x8*)(Bb + row*64 + ((fq*16) ^ (((row>>1)&3)<<4)));
      }
      #pragma unroll
      for (int n=0;n<4;++n)
        #pragma unroll
        for (int m=0;m<4;++m)
          acc[m][n] = __builtin_amdgcn_mfma_f32_16x16x32_bf16(af[m], bfr[n], acc[m][n],0,0,0);
    }
    __builtin_amdgcn_s_setprio(0);
    asm volatile("s_waitcnt vmcnt(0)" ::: "memory");
    __builtin_amdgcn_s_barrier();
    __builtin_amdgcn_sched_barrier(0);
  }

  const float* s1 = par; const float* t1 = par+512;
  for (int m=0;m<4;++m){
    int cb = c0 + wm*64 + m*16 + fq*4;
    float sc[4], sh[4];
    for (int j=0;j<4;++j){ sc[j]=s1[cb+j]; sh[j]=t1[cb+j]; }
    for (int n=0;n<4;++n){
      int gg = (int)g0 + wn*64 + n*16 + fr;
      int b = gg/196, p = gg - b*196;
      unsigned short hs[4];
      for (int j=0;j<4;++j){
        float v = fmaxf(acc[m][n][j]*sc[j]+sh[j], 0.f);
        unsigned short h = f2bf(v);
        hs[j] = h;
        size_t ic = (size_t)b*512 + cb + j;
        xhi[ic*256 + p] = h;
        xlo[ic*256 + p] = f2bf(v - bf2f(h));
      }
      *(short4v*)(xT + ((size_t)b*224 + p)*512 + cb) = *(short4v*)hs;
    }
  }
}

// ---------------- xxt = x @ x^T, split precision, triangle blocks ----------------
__global__ __launch_bounds__(256) void k_xxt(const unsigned short* __restrict__ xhi,
        const unsigned short* __restrict__ xlo, float* __restrict__ xxt){
  __shared__ char lds[32768];
  char* Als = lds; char* Bls = lds + 16384;
  int lin = blockIdx.x;                       // 1280 blocks
  int sz  = (lin&7)*160 + (lin>>3);
  int b = sz/10, sub = sz - b*10;
  unsigned mtp = (3u<<18)|(2u<<16)|(2u<<14)|(1u<<12)|(1u<<10)|(1u<<8)|(0u<<6)|(0u<<4)|(0u<<2)|0u;
  unsigned ntp = (3u<<18)|(3u<<16)|(2u<<14)|(3u<<12)|(2u<<10)|(1u<<8)|(3u<<6)|(2u<<4)|(1u<<2)|0u;
  int mt = (mtp>>(2*sub))&3, nt = (ntp>>(2*sub))&3;
  int c0 = mt*128, d0 = nt*128;
  int t = threadIdx.x, lane = t&63, wid = t>>6, wm = wid&1, wn = wid>>1;
  int fq = lane>>4, fr = lane&15;
  f32x4 acc[4][4] = {};
  for (int it=0; it<12; ++it){
    int seg = it>>2, kk0 = (it&3)*64;
    const unsigned short* As = (seg<2) ? xhi : xlo;
    const unsigned short* Bs = (seg==1) ? xlo : xhi;
    __syncthreads();
    #pragma unroll
    for (int r=0;r<4;++r){
      int L = r*256 + t;
      int row = L>>3, cs = ((L&7)^(row&7))*8;
      gl16(As + ((size_t)b*512 + c0 + row)*256 + kk0 + cs, Als + L*16);
      gl16(Bs + ((size_t)b*512 + d0 + row)*256 + kk0 + cs, Bls + L*16);
    }
    __syncthreads();
    #pragma unroll
    for (int ks=0; ks<2; ++ks){
      int kb = ks*64 + fq*16;
      bf16x8 af[4];
      #pragma unroll
      for (int m=0;m<4;++m){
        int row = wm*64 + m*16 + fr;
        af[m] = *(const bf16x8*)(Als + row*128 + (kb ^ ((row&7)<<4)));
      }
      #pragma unroll
      for (int n=0;n<4;++n){
        int row = wn*64 + n*16 + fr;
        bf16x8 bff = *(const bf16x8*)(Bls + row*128 + (kb ^ ((row&7)<<4)));
        #pragma unroll
        for (int m=0;m<4;++m)
          acc[m][n] = __builtin_amdgcn_mfma_f32_16x16x32_bf16(af[m], bff, acc[m][n],0,0,0);
      }
    }
  }
  for (int m=0;m<4;++m){
    int cb = c0 + wm*64 + m*16 + fq*4;
    for (int n=0;n<4;++n){
      int d = d0 + wn*64 + n*16 + fr;
      *(float4*)(xxt + ((size_t)b*512 + d)*512 + cb) = *(float4*)&acc[m][n];
    }
  }
  if (mt != nt){
    for (int m=0;m<4;++m){
      int cb = c0 + wm*64 + m*16 + fq*4;
      for (int n=0;n<4;++n){
        int d = d0 + wn*64 + n*16 + fr;
        for (int jj=0;jj<4;++jj)
          xxt[((size_t)b*512 + cb + jj)*512 + d] = acc[m][n][jj];
      }
    }
  }
}

// ---------------- softmax(-xxt) rows -> a (bf16) ----------------
__global__ __launch_bounds__(256) void k_softmax(const float* __restrict__ xxt, unsigned short* __restrict__ amat){
  int row = blockIdx.x*4 + (threadIdx.x>>6);
  int lane = threadIdx.x & 63;
  const float* src = xxt + (size_t)row*512 + lane*8;
  float4 v0 = *(const float4*)src;
  float4 v1 = *(const float4*)(src+4);
  float mn = fminf(fminf(fminf(v0.x,v0.y),fminf(v0.z,v0.w)),
                   fminf(fminf(v1.x,v1.y),fminf(v1.z,v1.w)));
  for (int m=32; m; m>>=1) mn = fminf(mn, __shfl_xor(mn, m, 64));
  float e[8];
  e[0]=__expf(mn-v0.x); e[1]=__expf(mn-v0.y); e[2]=__expf(mn-v0.z); e[3]=__expf(mn-v0.w);
  e[4]=__expf(mn-v1.x); e[5]=__expf(mn-v1.y); e[6]=__expf(mn-v1.z); e[7]=__expf(mn-v1.w);
  float s = e[0]+e[1]+e[2]+e[3]+e[4]+e[5]+e[6]+e[7];
  for (int m=32; m; m>>=1) s += __shfl_xor(s, m, 64);
  float inv = 1.f/s;
  short4v p0, p1;
  for (int q=0;q<4;++q) p0[q] = (short)f2bf(e[q]*inv);
  for (int q=0;q<4;++q) p1[q] = (short)f2bf(e[4+q]*inv);
  unsigned short* dst = amat + (size_t)row*512 + lane*8;
  *(short4v*)dst = p0;
  *(short4v*)(dst+4) = p1;
}

// ---------------- PV: y = a @ x -> ypad [b][ci0b 8][prow 256][cio 64] ----------------
__global__ __launch_bounds__(256) void k_pv(const unsigned short* __restrict__ amat,
        const unsigned short* __restrict__ xT, unsigned short* __restrict__ ypad){
  __shared__ char lds[30720];
  char* Als = lds; char* Bls = lds + 16384;
  int lin = blockIdx.x, per = gridDim.x>>3;
  int sz  = (lin&7)*per + (lin>>3);
  int b = sz>>3, sub = sz&7, mt = sub>>1, nt = sub&1;
  int c0 = mt*128, n0 = nt*112;
  int t = threadIdx.x, lane = t&63, wid = t>>6;
  int fq = lane>>4, fr = lane&15;
  f32x4 acc[2][7] = {};
  for (int it=0; it<8; ++it){
    int k0 = it*64;
    __syncthreads();
    #pragma unroll
    for (int r=0;r<4;++r){
      int L = r*256 + t;
      int row = L>>3, cs = ((L&7)^(row&7))*8;
      gl16(amat + ((size_t)b*512 + c0 + row)*512 + k0 + cs, Als + L*16);
    }
    #pragma unroll
    for (int r=0;r<4;++r){
      int L = r*256 + t;
      if (L < 896){
        int row = L>>3, cs = ((L&7)^(row&7))*8;
        gl16(xT + ((size_t)b*224 + n0 + row)*512 + k0 + cs, Bls + L*16);
      }
    }
    __syncthreads();
    #pragma unroll
    for (int ks=0; ks<2; ++ks){
      int kb = ks*64 + fq*16;
      bf16x8 af[2];
      #pragma unroll
      for (int m=0;m<2;++m){
        int row = wid*32 + m*16 + fr;
        af[m] = *(const bf16x8*)(Als + row*128 + (kb ^ ((row&7)<<4)));
      }
      #pragma unroll
      for (int n=0;n<7;++n){
        int row = n*16 + fr;
        bf16x8 bff = *(const bf16x8*)(Bls + row*128 + (kb ^ ((row&7)<<4)));
        #pragma unroll
        for (int m=0;m<2;++m)
          acc[m][n] = __builtin_amdgcn_mfma_f32_16x16x32_bf16(af[m], bff, acc[m][n],0,0,0);
      }
    }
  }
  for (int m=0;m<2;++m){
    int cb = c0 + wid*32 + m*16 + fq*4;
    int ci0b = cb>>6, cio = cb&63;
    for (int n=0;n<7;++n){
      int p = n0 + n*16 + fr;
      if (p < 196){
        int hh = p/14, wwp = p - hh*14;
        int prow = (hh+1)*16 + (wwp+1);
        short4v pk;
        for (int j=0;j<4;++j) pk[j] = (short)f2bf(acc[m][n][j]);
        *(short4v*)(ypad + (((size_t)b*8 + ci0b)*256 + prow)*64 + cio) = pk;
      }
    }
  }
}

// ---------------- conv3 implicit GEMM + BN2 + ReLU + avgpool -> zbar (sum) ----------------
__global__ __launch_bounds__(512, 4) void k_conv3(const unsigned short* __restrict__ ypad,
        const unsigned short* __restrict__ w3c, const float* __restrict__ par,
        float* __restrict__ zbar){
  __shared__ char lds[65536];
  char* WIN = lds;                 // [256][64] bf16, swizzled
  char* AB0 = lds + 32768;
  char* AB1 = lds + 49152;
  int bx = blockIdx.x;             // 512 blocks
  int xcd = bx&7, jj2 = bx>>3;
  int b = xcd*16 + (jj2>>2), cot = jj2&3;
  int c0 = cot*128;
  int t = threadIdx.x, lane = t&63, w = t>>6;
  int wm = w>>1, wn = w&1;
  int fq = lane>>4, fr = lane&15;
  int frB = (fr<14) ? fr : 13;
  bool pok = (fr<14);
  f32x4 acc[2][7] = {};
  for (int ci0=0; ci0<8; ++ci0){
    const unsigned short* wsrc = ypad + ((size_t)(b*8 + ci0)*256)*64;
    #pragma unroll
    for (int r=0;r<4;++r){
      int L = r*512 + t;
      int row = L>>3, cs = ((L&7)^(row&7))*8;
      gl16(wsrc + row*64 + cs, WIN + L*16);
    }
    {
      const unsigned short* asrc = w3c + ((size_t)(ci0*9 + 0)*512 + c0)*64;
      #pragma unroll
      for (int r=0;r<2;++r){
        int L = r*512 + t;
        int row = L>>3, cs = ((L&7)^(row&7))*8;
        gl16(asrc + row*64 + cs, AB0 + L*16);
      }
    }
    __syncthreads();
    for (int tap=0; tap<9; ++tap){
      char* Acur = (tap&1) ? AB1 : AB0;
      char* Anxt = (tap&1) ? AB0 : AB1;
      if (tap < 8){
        const unsigned short* asrc = w3c + ((size_t)(ci0*9 + tap+1)*512 + c0)*64;
        #pragma unroll
        for (int r=0;r<2;++r){
          int L = r*512 + t;
          int row = L>>3, cs = ((L&7)^(row&7))*8;
          gl16(asrc + row*64 + cs, Anxt + L*16);
        }
      }
      int kh = tap/3, kw = tap - kh*3;
      bf16x8 ah[2][2];
      #pragma unroll
      for (int ks=0;ks<2;++ks)
        #pragma unroll
        for (int m=0;m<2;++m){
          int row = wm*32 + m*16 + fr;
          ah[ks][m] = *(const bf16x8*)(Acur + row*128 + (((ks*4+fq)^(row&7))<<4));
        }
      int col = frB + kw;
      __builtin_amdgcn_s_setprio(1);
      #pragma unroll
      for (int n=0;n<7;++n){
        int prow = (wn*7 + n + kh)*16 + col;
        #pragma unroll
        for (int ks=0;ks<2;++ks){
          bf16x8 bf = *(const bf16x8*)(WIN + prow*128 + (((ks*4+fq)^(prow&7))<<4));
          acc[0][n] = __builtin_amdgcn_mfma_f32_16x16x32_bf16(ah[ks][0], bf, acc[0][n],0,0,0);
          acc[1][n] = __builtin_amdgcn_mfma_f32_16x16x32_bf16(ah[ks][1], bf, acc[1][n],0,0,0);
        }
      }
      __builtin_amdgcn_s_setprio(0);
      __syncthreads();
    }
  }
  const float* s2 = par+1024; const float* t2 = par+1536;
  float ps[2][4];
  #pragma unroll
  for (int m=0;m<2;++m){
    int cb = c0 + wm*32 + m*16 + fq*4;
    #pragma unroll
    for (int j=0;j<4;++j){
      float sc = s2[cb+j], sh = t2[cb+j];
      float s = 0.f;
      #pragma unroll
      for (int n=0;n<7;++n)
        s += fmaxf(acc[m][n][j]*sc + sh, 0.f);
      ps[m][j] = pok ? s : 0.f;
    }
  }
  #pragma unroll
  for (int off=1; off<16; off<<=1)
    #pragma unroll
    for (int m=0;m<2;++m)
      #pragma unroll
      for (int j=0;j<4;++j)
        ps[m][j] += __shfl_xor(ps[m][j], off, 64);
  float* part = (float*)lds;
  if (fr == 0){
    #pragma unroll
    for (int m=0;m<2;++m)
      #pragma unroll
      for (int j=0;j<4;++j)
        part[wn*128 + wm*32 + m*16 + fq*4 + j] = ps[m][j];
  }
  __syncthreads();
  if (t < 128)
    zbar[(size_t)b*512 + c0 + t] = part[t] + part[128 + t];
}

// ---------------- fc1(relu) + fc2 ----------------
__global__ __launch_bounds__(256) void k_fc(const float* __restrict__ zbar,
        const float* __restrict__ fc1T, const float* __restrict__ fc1b,
        const float* __restrict__ fc2T, const float* __restrict__ fc2b,
        float* __restrict__ out){
  __shared__ float zb[512];
  __shared__ float hl[200];
  int b = blockIdx.x, t = threadIdx.x;
  zb[t]     = zbar[(size_t)b*512 + t]       * (1.f/196.f);
  zb[t+256] = zbar[(size_t)b*512 + t + 256] * (1.f/196.f);
  __syncthreads();
  if (t < 200){
    float acc = fc1b[t];
    for (int k=0;k<512;++k) acc += zb[k]*fc1T[k*200+t];
    hl[t] = fmaxf(acc, 0.f);
  }
  __syncthreads();
  if (t < 200){
    float acc = fc2b[t];
    for (int k=0;k<200;++k) acc += hl[k]*fc2T[k*200+t];
    out[(size_t)b*200 + t] = acc;
  }
}

extern "C" void kernel_launch(void* const* d_in, const int* in_sizes, int n_in,
                              void* d_out, int out_size, void* d_ws, size_t ws_size,
                              hipStream_t stream) {
  const float* feature  = (const float*)d_in[0];
  const float* w_reduce = (const float*)d_in[1];
  const float* b_reduce = (const float*)d_in[2];
  const float* g1  = (const float*)d_in[3];
  const float* be1 = (const float*)d_in[4];
  const float* m1  = (const float*)d_in[5];
  const float* v1  = (const float*)d_in[6];
  const float* w3  = (const float*)d_in[7];
  const float* b3  = (const float*)d_in[8];
  const float* g2  = (const float*)d_in[9];
  const float* be2 = (const float*)d_in[10];
  const float* m2  = (const float*)d_in[11];
  const float* v2  = (const float*)d_in[12];
  const float* fc1w = (const float*)d_in[13];
  const float* fc1b = (const float*)d_in[14];
  const float* fc2w = (const float*)d_in[15];
  const float* fc2b = (const float*)d_in[16];

  char* ws = (char*)d_ws;
  unsigned short* fhi  = (unsigned short*)(ws + O_FHI);
  unsigned short* flo  = (unsigned short*)(ws + O_FLO);
  float*          xxt  = (float*)(ws + O_FHI);      // aliases fhi (dead after conv1)
  unsigned short* xhi  = (unsigned short*)(ws + O_XHI);
  unsigned short* xlo  = (unsigned short*)(ws + O_XLO);
  unsigned short* ypad = (unsigned short*)(ws + O_XLO);  // aliases xlo (dead after xxt)
  unsigned short* xT   = (unsigned short*)(ws + O_XT);
  unsigned short* amat = (unsigned short*)(ws + O_AMAT);
  unsigned short* wh   = (unsigned short*)(ws + O_WH);
  unsigned short* wl   = (unsigned short*)(ws + O_WL);
  unsigned short* w3c  = (unsigned short*)(ws + O_W3B);
  float* par  = (float*)(ws + O_PAR);
  float* fc1T = (float*)(ws + O_FC1T);
  float* fc2T = (float*)(ws + O_FC2T);
  float* zbar = (float*)(ws + O_ZBAR);

  k_params<<<2, 256, 0, stream>>>(b_reduce, g1, be1, m1, v1, b3, g2, be2, m2, v2, par);
  k_wrhl<<<dim3(8,512), 256, 0, stream>>>(w_reduce, wh, wl);
  k_w3c<<<dim3(18,512), 256, 0, stream>>>(w3, w3c);
  k_fc1t<<<400, 256, 0, stream>>>(fc1w, fc1T);
  k_fc2t<<<157, 256, 0, stream>>>(fc2w, fc2T);
  k_zeropad<<<256, 256, 0, stream>>>(xhi, xlo);

  k_featT<<<dim3(7,32,128), 256, 0, stream>>>(feature, fhi, flo);
  k_conv1<<<784, 256, 0, stream>>>(fhi, flo, wh, wl, par, xhi, xlo, xT);

  k_xxt<<<1280, 256, 0, stream>>>(xhi, xlo, xxt);
  k_softmax<<<16384, 256, 0, stream>>>(xxt, amat);

  k_zeroyb<<<1024, 256, 0, stream>>>(ypad);        // xlo dead; ypad borders -> 0
  k_pv<<<1024, 256, 0, stream>>>(amat, xT, ypad);
  k_conv3<<<512, 512, 0, stream>>>(ypad, w3c, par, zbar);
  k_fc<<<128, 256, 0, stream>>>(zbar, fc1T, fc1b, fc2T, fc2b, (float*)d_out);
}